// Round 9
// baseline (365.722 us; speedup 1.0000x reference)
//
#include <hip/hip_runtime.h>
#include <hip/hip_bf16.h>

// TT layer via bf16 MFMA (gfx950), NB=4 batches per WG, 16 waves (1024 thr).
//   Phase A: z1[b][k'=m2*16+r][m3]  = core0[n1]^T . x[b]       (MFMA K=32)
//   Phase B: z2[b][k2=m3*16+s'][n2] = A1[512,512] . z1         (MFMA, K=512)
//            16 waves = 8 M-groups x 2 N-groups; wave tile M=64 x N=64
//            -> acc[4][4] (fits 128-reg budget at 4 waves/SIMD)
//   Phase C: y[b][n2,n3] = z2 . W2T^T + bias                   (MFMA K=512)
// WG = (b-quad, n1): 2048 WGs x 1024 threads, 128KB dynamic LDS (4 x 32KB
// z-tile; z2 overwrites z1 after barrier). 4 waves/SIMD for latency hiding
// at UNCHANGED per-WG traffic (the R7 occupancy test was confounded by 2x A1).
// LDS z-tile layout (32 KB per b): element (k 0..511, c 0..31) at byte
//   (k>>5)*2048 + c*64 + (((k&31)<<1) ^ ((c>>1&1)<<5))   [conflict-free b128]
// XCD-swizzled blockIdx; d_ws (bf16): A1[(n2*16+s')][(m2*16+r)],
//   A0T[(n1*16+s)][m1], W2T[n3][(m3*16+s')], xT[b][p][m1].
// bf16 conversion via __float22bfloat162_rn -> v_cvt_pk_bf16_f32 (VALU cut).

typedef __attribute__((ext_vector_type(8))) short bf16x8;
typedef __attribute__((ext_vector_type(4))) float f32x4;

#define WS_A1   0
#define WS_A0T  262144
#define WS_W2T  278528
#define WS_XT   294912
#define WS_XT_ELEMS 8388608
#define WS_NEED_BYTES ((size_t)(WS_XT + WS_XT_ELEMS) * 2)

__device__ __forceinline__ unsigned short f2bf(float f) {
    union { float f; unsigned int u; } v; v.f = f;
    unsigned int u = v.u;
    u += 0x7fffu + ((u >> 16) & 1u);   // RNE (inputs finite)
    return (unsigned short)(u >> 16);
}

__device__ __forceinline__ unsigned int cvt2(float a, float b) {
    union { __hip_bfloat162 h; unsigned int u; } v;
    v.h = __float22bfloat162_rn(float2{a, b});   // v_cvt_pk_bf16_f32
    return v.u;
}

// ---------------- prep: core transforms (+ optional x transpose) ----------------
template<bool XT>
__global__ void tt_prep(const float* __restrict__ x,
                        const float* __restrict__ core0,
                        const float* __restrict__ core1,
                        const float* __restrict__ core2,
                        unsigned short* __restrict__ ws)
{
    const int t = threadIdx.x;
    if (XT && blockIdx.x < 8192) {
        // transpose x[b][m1][m2*32+m3] (f32) -> xT[b][p=m2*32+m3][m1] (bf16)
        __shared__ float tile[32 * 36];
        const int b  = blockIdx.x >> 5;
        const int m2 = blockIdx.x & 31;
        {
            const int m1 = t >> 3, c4 = (t & 7) * 4;
            float4 v = *(const float4*)(x + (size_t)b * 32768 + m1 * 1024 + m2 * 32 + c4);
            *(float4*)&tile[m1 * 36 + c4] = v;
        }
        __syncthreads();
        {
            const int m3 = t >> 3, g = t & 7;
            unsigned short o[4];
            #pragma unroll
            for (int j = 0; j < 4; ++j)
                o[j] = f2bf(tile[(g * 4 + j) * 36 + m3]);
            unsigned short* dst = ws + WS_XT + (size_t)b * 32768 + (m2 * 32 + m3) * 32 + g * 4;
            *(uint2*)dst = *(uint2*)o;
        }
        return;
    }
    const int u = (blockIdx.x - (XT ? 8192 : 0)) * 256 + t;
    unsigned short* A1  = ws + WS_A1;    // [512 rows=(n2*16+s')][512 cols=(m2*16+r)]
    unsigned short* A0T = ws + WS_A0T;   // [512 rows=(n1*16+s)][32 m1]
    unsigned short* W2T = ws + WS_W2T;   // [32 n3][512 k2=(m3*16+s')]
    bf16x8 o;
    if (u < 32768) {
        int e = u * 8;
        int row = e >> 9, col0 = e & 511;
        int n2 = row >> 4, s = row & 15;
        int m2 = col0 >> 4, r0 = col0 & 15;   // r0 in {0,8}
        const float* src = core1 + n2 * 512 + m2 * 16 + s;
        #pragma unroll
        for (int j = 0; j < 8; ++j) o[j] = (short)f2bf(src[(r0 + j) * 16384]);
        *(bf16x8*)(A1 + e) = o;
    } else if (u < 34816) {
        int e = (u - 32768) * 8;
        int row = e >> 5, m1b = e & 31;    // row = n1*16 + s
        int n1 = row >> 4, s = row & 15;
        const float* src = core0 + n1 * 512 + m1b * 16 + s;
        #pragma unroll
        for (int j = 0; j < 8; ++j) o[j] = (short)f2bf(src[j * 16]);
        *(bf16x8*)(A0T + e) = o;
    } else if (u < 36864) {
        int e = (u - 34816) * 8;
        int n3 = e >> 9, k20 = e & 511;
        int m3 = k20 >> 4, s0 = k20 & 15;  // s0 in {0,8}
        const float* src = core2 + n3 * 32 + m3;
        #pragma unroll
        for (int j = 0; j < 8; ++j) o[j] = (short)f2bf(src[(s0 + j) * 1024]);
        *(bf16x8*)(W2T + e) = o;
    }
}

// ---------------- main fused kernel ----------------
template<bool XT>
__global__ __launch_bounds__(1024, 4)
void tt_mfma(const float* __restrict__ x,
             const unsigned short* __restrict__ ws,
             const float* __restrict__ bias,
             float* __restrict__ out)
{
    extern __shared__ char smem[];   // 4 x 32KB: z-tile per local b

    const unsigned short* A1  = ws + WS_A1;
    const unsigned short* A0T = ws + WS_A0T;
    const unsigned short* W2T = ws + WS_W2T;
    const unsigned short* xT  = ws + WS_XT;

    const int t   = threadIdx.x;
    const int l   = t & 63;
    const int w   = t >> 6;        // wave 0..15
    const int l15 = l & 15;
    const int lg  = l >> 4;        // 0..3

    // XCD-aware bijective swizzle: 2048 WGs, 8 XCDs, 256 per XCD.
    const int swzid = (blockIdx.x & 7) * 256 + (blockIdx.x >> 3);
    const int bq = swzid >> 5;
    const int n1 = swzid & 31;

    const int swz5 = ((l15 >> 1) & 1) << 5;

    // ---- Phase A: wave -> (lb = w>>2, quarter q = w&3); 16 MFMAs, dbuf'd ----
    {
        const int lb = w >> 2, q = w & 3;
        const int b  = bq * 4 + lb;
        char* zb = smem + lb * 32768;
        bf16x8 afrag = *(const bf16x8*)(A0T + n1 * 512 + l15 * 32 + lg * 8);
        if (XT) {
            const unsigned short* xb = xT + (size_t)b * 32768 + lg * 8;
            bf16x8 bfrag[2];
            bfrag[0] = *(const bf16x8*)(xb + (q * 256 + l15) * 32);
            #pragma unroll
            for (int pti = 0; pti < 16; ++pti) {
                if (pti < 15) {
                    int pn = q * 256 + (pti + 1) * 16 + l15;
                    bfrag[(pti + 1) & 1] = *(const bf16x8*)(xb + pn * 32);
                }
                int p = q * 256 + pti * 16 + l15;
                f32x4 c = __builtin_amdgcn_mfma_f32_16x16x32_bf16(
                    afrag, bfrag[pti & 1], (f32x4){0.f, 0.f, 0.f, 0.f}, 0, 0, 0);
                int m2 = p >> 5, m3 = p & 31;
                uint2 h;
                h.x = cvt2(c[0], c[1]);
                h.y = cvt2(c[2], c[3]);
                // k' = m2*16 + (lg*4+i): chunk = m2>>1, within = (m2&1)*32+lg*8
                int off = ((m2 >> 1) << 11) + (m3 << 6) +
                          ((((m2 & 1) << 5) + (lg << 3)) ^ (((m3 >> 1) & 1) << 5));
                *(uint2*)(zb + off) = h;
            }
        } else {
            const float* xb = x + (size_t)b * 32768 + (lg * 8) * 1024;
            for (int pti = 0; pti < 16; ++pti) {
                int p = q * 256 + pti * 16 + l15;
                bf16x8 bfrag;
                #pragma unroll
                for (int j = 0; j < 8; ++j) bfrag[j] = (short)f2bf(xb[j * 1024 + p]);
                f32x4 c = __builtin_amdgcn_mfma_f32_16x16x32_bf16(
                    afrag, bfrag, (f32x4){0.f, 0.f, 0.f, 0.f}, 0, 0, 0);
                int m2 = p >> 5, m3 = p & 31;
                uint2 h;
                h.x = cvt2(c[0], c[1]);
                h.y = cvt2(c[2], c[3]);
                int off = ((m2 >> 1) << 11) + (m3 << 6) +
                          ((((m2 & 1) << 5) + (lg << 3)) ^ (((m3 >> 1) & 1) << 5));
                *(uint2*)(zb + off) = h;
            }
        }
    }
    __syncthreads();

    // ---- Phase B: wave = (mg = w>>1, ng = w&1) ----
    // M rows [mg*64, mg*64+64); N = 64 cols = b-pair {2ng, 2ng+1} x 32 m3.
    f32x4 acc[4][4];
    #pragma unroll
    for (int mt = 0; mt < 4; ++mt)
        #pragma unroll
        for (int nt = 0; nt < 4; ++nt)
            acc[mt][nt] = (f32x4){0.f, 0.f, 0.f, 0.f};
    {
        const int mg = w >> 1, ng = w & 1;
        const unsigned short* a1p = A1 + (mg * 64 + l15) * 512 + lg * 8;
        const int kofs = (lg << 4) ^ swz5;        // within-chunk byte for reads
        const int rlo = (l15 << 6) + kofs;        // c = l15
        const int rhi = rlo + 1024;               // c = 16 + l15
        char* zb0 = smem + (ng * 2 + 0) * 32768;
        char* zb1 = smem + (ng * 2 + 1) * 32768;

        #pragma unroll 2
        for (int ks = 0; ks < 16; ++ks) {
            bf16x8 af[4], bf[4];
            #pragma unroll
            for (int mt = 0; mt < 4; ++mt)
                af[mt] = *(const bf16x8*)(a1p + mt * 8192 + ks * 32);
            bf[0] = *(const bf16x8*)(zb0 + ks * 2048 + rlo);
            bf[1] = *(const bf16x8*)(zb0 + ks * 2048 + rhi);
            bf[2] = *(const bf16x8*)(zb1 + ks * 2048 + rlo);
            bf[3] = *(const bf16x8*)(zb1 + ks * 2048 + rhi);
            #pragma unroll
            for (int mt = 0; mt < 4; ++mt)
                #pragma unroll
                for (int nt = 0; nt < 4; ++nt)
                    acc[mt][nt] = __builtin_amdgcn_mfma_f32_16x16x32_bf16(
                        af[mt], bf[nt], acc[mt][nt], 0, 0, 0);
        }
    }
    __syncthreads();   // all z1 reads complete

    // write z2 (bf16): element (k2 = m3*16 + s', n2); s' = lg*4+i -> b64 stores
    {
        const int mg = w >> 1, ng = w & 1;
        #pragma unroll
        for (int mt = 0; mt < 4; ++mt) {
            int n2 = mg * 4 + mt;
            int nsw = ((n2 >> 1) & 1) << 5;
            #pragma unroll
            for (int nt = 0; nt < 4; ++nt) {
                char* zb = smem + (ng * 2 + (nt >> 1)) * 32768;
                int m3 = (nt & 1) * 16 + l15;
                uint2 h;
                h.x = cvt2(acc[mt][nt][0], acc[mt][nt][1]);
                h.y = cvt2(acc[mt][nt][2], acc[mt][nt][3]);
                // chunk = m3>>1, within = (m3&1)*32 + lg*8, row byte = n2*64
                int off = ((m3 >> 1) << 11) + (n2 << 6) +
                          ((((m3 & 1) << 5) + (lg << 3)) ^ nsw);
                *(uint2*)(zb + off) = h;
            }
        }
    }
    __syncthreads();

    // ---- Phase C: wave -> (lb = w>>2, n2h = (w>>1)&1, n3h = w&1) ----
    {
        const int lb = w >> 2, n2h = (w >> 1) & 1, n3h = w & 1;
        const int b  = bq * 4 + lb;
        char* zb = smem + lb * 32768;
        f32x4 c = (f32x4){0.f, 0.f, 0.f, 0.f};
        const unsigned short* w2p = W2T + (n3h * 16 + l15) * 512 + lg * 8;
        const int kofs = (lg << 4) ^ swz5;
        const int n2row = n2h * 16 + l15;
        #pragma unroll 2
        for (int ks = 0; ks < 16; ++ks) {
            bf16x8 bfg = *(const bf16x8*)(w2p + ks * 32);
            bf16x8 af  = *(const bf16x8*)(zb + ks * 2048 + (n2row << 6) + kofs);
            c = __builtin_amdgcn_mfma_f32_16x16x32_bf16(af, bfg, c, 0, 0, 0);
        }
        int n3 = n3h * 16 + l15;
        size_t ob = (size_t)b * 32768 + (size_t)n1 * 1024;
        const float* bp2 = bias + n1 * 1024;
        #pragma unroll
        for (int i = 0; i < 4; ++i) {
            int n2 = n2h * 16 + lg * 4 + i;
            out[ob + n2 * 32 + n3] = c[i] + bp2[n2 * 32 + n3];
        }
    }
}

extern "C" void kernel_launch(void* const* d_in, const int* in_sizes, int n_in,
                              void* d_out, int out_size, void* d_ws, size_t ws_size,
                              hipStream_t stream) {
    (void)in_sizes; (void)n_in; (void)out_size;
    const float* x     = (const float*)d_in[0];
    const float* core0 = (const float*)d_in[1];
    const float* core1 = (const float*)d_in[2];
    const float* core2 = (const float*)d_in[3];
    const float* bias  = (const float*)d_in[4];
    float* out = (float*)d_out;
    unsigned short* ws = (unsigned short*)d_ws;

    const int lds_bytes = 4 * 32768;   // 128 KB -> 1 WG/CU, 16 waves
    if (ws_size >= WS_NEED_BYTES) {
        hipFuncSetAttribute((const void*)tt_mfma<true>,
                            hipFuncAttributeMaxDynamicSharedMemorySize, lds_bytes);
        tt_prep<true><<<8336, 256, 0, stream>>>(x, core0, core1, core2, ws);
        tt_mfma<true><<<2048, 1024, lds_bytes, stream>>>(x, ws, bias, out);
    } else {
        hipFuncSetAttribute((const void*)tt_mfma<false>,
                            hipFuncAttributeMaxDynamicSharedMemorySize, lds_bytes);
        tt_prep<false><<<144, 256, 0, stream>>>(x, core0, core1, core2, ws);
        tt_mfma<false><<<2048, 1024, lds_bytes, stream>>>(x, ws, bias, out);
    }
}

// Round 10
// 274.234 us; speedup vs baseline: 1.3336x; 1.3336x over previous
//
#include <hip/hip_runtime.h>
#include <hip/hip_bf16.h>

// TT layer via bf16 MFMA (gfx950), NB=2, m97-style global_load_lds K-loop.
//   Phase A: z1[b][k'=m2*16+r][m3]  = core0[n1]^T . x[b]       (MFMA K=32)
//   Phase B: z2[b][k2=m3*16+s'][n2] = A1[512,512] . z1  (K=512 in 16 slices;
//            each 32KB A1 slice staged to LDS via global_load_lds dbuf)
//   Phase C: y[b][n2,n3] = z2 . W2T^T + bias                   (MFMA K=512)
// WG = (b-pair, n1): 4096 WGs x 512 thr, 128KB LDS =
//   [0,64K): 2 z-tiles (32KB/b, conflict-free layout:
//     elem(k,c) at (k>>5)*2048 + c*64 + ((k&31)*2 ^ ((c>>1&1)<<5)))
//   [64K,128K): A1 slice dbuf (2 x 32KB; slice = [512 rows][32 cols] row-major)
// d_ws (bf16): A1s[ks][512][32] (slice-major!), A0T[(n1*16+s)][m1],
//   W2T[n3][(m3*16+s')], xT[b][p][m1]. XCD-swizzled blockIdx.

typedef __attribute__((ext_vector_type(8))) short bf16x8;
typedef __attribute__((ext_vector_type(4))) float f32x4;

#define WS_A1   0
#define WS_A0T  262144
#define WS_W2T  278528
#define WS_XT   294912
#define WS_XT_ELEMS 8388608
#define WS_NEED_BYTES ((size_t)(WS_XT + WS_XT_ELEMS) * 2)

__device__ __forceinline__ unsigned short f2bf(float f) {
    union { float f; unsigned int u; } v; v.f = f;
    unsigned int u = v.u;
    u += 0x7fffu + ((u >> 16) & 1u);   // RNE (inputs finite)
    return (unsigned short)(u >> 16);
}

__device__ __forceinline__ unsigned int cvt2(float a, float b) {
    union { __hip_bfloat162 h; unsigned int u; } v;
    v.h = __float22bfloat162_rn(float2{a, b});   // v_cvt_pk_bf16_f32
    return v.u;
}

// ---------------- prep: core transforms (+ optional x transpose) ----------------
template<bool XT>
__global__ void tt_prep(const float* __restrict__ x,
                        const float* __restrict__ core0,
                        const float* __restrict__ core1,
                        const float* __restrict__ core2,
                        unsigned short* __restrict__ ws)
{
    const int t = threadIdx.x;
    if (XT && blockIdx.x < 8192) {
        // transpose x[b][m1][m2*32+m3] (f32) -> xT[b][p=m2*32+m3][m1] (bf16)
        __shared__ float tile[32 * 36];
        const int b  = blockIdx.x >> 5;
        const int m2 = blockIdx.x & 31;
        {
            const int m1 = t >> 3, c4 = (t & 7) * 4;
            float4 v = *(const float4*)(x + (size_t)b * 32768 + m1 * 1024 + m2 * 32 + c4);
            *(float4*)&tile[m1 * 36 + c4] = v;
        }
        __syncthreads();
        {
            const int m3 = t >> 3, g = t & 7;
            unsigned short o[4];
            #pragma unroll
            for (int j = 0; j < 4; ++j)
                o[j] = f2bf(tile[(g * 4 + j) * 36 + m3]);
            unsigned short* dst = ws + WS_XT + (size_t)b * 32768 + (m2 * 32 + m3) * 32 + g * 4;
            *(uint2*)dst = *(uint2*)o;
        }
        return;
    }
    const int u = (blockIdx.x - (XT ? 8192 : 0)) * 256 + t;
    unsigned short* A1  = ws + WS_A1;    // [ks][row=(n2*16+s)][cw] slice-major
    unsigned short* A0T = ws + WS_A0T;   // [512 rows=(n1*16+s)][32 m1]
    unsigned short* W2T = ws + WS_W2T;   // [32 n3][512 k2=(m3*16+s')]
    bf16x8 o;
    if (u < 32768) {
        int e = u * 8;
        int ks  = e >> 14;
        int rem = e & 16383;
        int row = rem >> 5, cw0 = rem & 31;
        int n2 = row >> 4, s = row & 15;
        #pragma unroll
        for (int j = 0; j < 8; ++j) {
            int col = ks * 32 + cw0 + j;          // col = m2*16 + r
            int m2 = col >> 4, r = col & 15;
            o[j] = (short)f2bf(core1[r * 16384 + n2 * 512 + m2 * 16 + s]);
        }
        *(bf16x8*)(A1 + e) = o;
    } else if (u < 34816) {
        int e = (u - 32768) * 8;
        int row = e >> 5, m1b = e & 31;    // row = n1*16 + s
        int n1 = row >> 4, s = row & 15;
        const float* src = core0 + n1 * 512 + m1b * 16 + s;
        #pragma unroll
        for (int j = 0; j < 8; ++j) o[j] = (short)f2bf(src[j * 16]);
        *(bf16x8*)(A0T + e) = o;
    } else if (u < 36864) {
        int e = (u - 34816) * 8;
        int n3 = e >> 9, k20 = e & 511;
        int m3 = k20 >> 4, s0 = k20 & 15;  // s0 in {0,8}
        const float* src = core2 + n3 * 32 + m3;
        #pragma unroll
        for (int j = 0; j < 8; ++j) o[j] = (short)f2bf(src[(s0 + j) * 1024]);
        *(bf16x8*)(W2T + e) = o;
    }
}

// ---------------- main fused kernel ----------------
template<bool XT>
__global__ __launch_bounds__(512, 2)
void tt_mfma(const float* __restrict__ x,
             const unsigned short* __restrict__ ws,
             const float* __restrict__ bias,
             float* __restrict__ out)
{
    extern __shared__ char smem[];   // [0,64K): z-tiles; [64K,128K): A1 dbuf

    const unsigned short* A1  = ws + WS_A1;
    const unsigned short* A0T = ws + WS_A0T;
    const unsigned short* W2T = ws + WS_W2T;
    const unsigned short* xT  = ws + WS_XT;

    const int t   = threadIdx.x;
    const int l   = t & 63;
    const int w   = t >> 6;        // wave 0..7
    const int l15 = l & 15;
    const int lg  = l >> 4;        // 0..3

    // XCD-aware bijective swizzle: 4096 WGs, 8 XCDs, 512 per XCD.
    const int swzid = (blockIdx.x & 7) * 512 + (blockIdx.x >> 3);
    const int bq = swzid >> 5;     // b-pair 0..127
    const int n1 = swzid & 31;

    const int swz5 = ((l15 >> 1) & 1) << 5;

    // ---- Phase A: wave -> (lb = w>>2, quarter q = w&3); 16 MFMAs ----
    {
        const int lb = w >> 2, q = w & 3;
        const int b  = bq * 2 + lb;
        char* zb = smem + lb * 32768;
        bf16x8 afrag = *(const bf16x8*)(A0T + n1 * 512 + l15 * 32 + lg * 8);
        if (XT) {
            const unsigned short* xb = xT + (size_t)b * 32768 + lg * 8;
            bf16x8 bfrag[2];
            bfrag[0] = *(const bf16x8*)(xb + (q * 256 + l15) * 32);
            #pragma unroll
            for (int pti = 0; pti < 16; ++pti) {
                if (pti < 15) {
                    int pn = q * 256 + (pti + 1) * 16 + l15;
                    bfrag[(pti + 1) & 1] = *(const bf16x8*)(xb + pn * 32);
                }
                int p = q * 256 + pti * 16 + l15;
                f32x4 c = __builtin_amdgcn_mfma_f32_16x16x32_bf16(
                    afrag, bfrag[pti & 1], (f32x4){0.f, 0.f, 0.f, 0.f}, 0, 0, 0);
                int m2 = p >> 5, m3 = p & 31;
                uint2 h;
                h.x = cvt2(c[0], c[1]);
                h.y = cvt2(c[2], c[3]);
                int off = ((m2 >> 1) << 11) + (m3 << 6) +
                          ((((m2 & 1) << 5) + (lg << 3)) ^ (((m3 >> 1) & 1) << 5));
                *(uint2*)(zb + off) = h;
            }
        } else {
            const float* xb = x + (size_t)b * 32768 + (lg * 8) * 1024;
            for (int pti = 0; pti < 16; ++pti) {
                int p = q * 256 + pti * 16 + l15;
                bf16x8 bfrag;
                #pragma unroll
                for (int j = 0; j < 8; ++j) bfrag[j] = (short)f2bf(xb[j * 1024 + p]);
                f32x4 c = __builtin_amdgcn_mfma_f32_16x16x32_bf16(
                    afrag, bfrag, (f32x4){0.f, 0.f, 0.f, 0.f}, 0, 0, 0);
                int m2 = p >> 5, m3 = p & 31;
                uint2 h;
                h.x = cvt2(c[0], c[1]);
                h.y = cvt2(c[2], c[3]);
                int off = ((m2 >> 1) << 11) + (m3 << 6) +
                          ((((m2 & 1) << 5) + (lg << 3)) ^ (((m3 >> 1) & 1) << 5));
                *(uint2*)(zb + off) = h;
            }
        }
    }

    // ---- Phase B: wave w owns M rows [w*64, +64); N = 64 (2 b x 32 m3) ----
    // A1 slices staged LDS-direct (global_load_lds x4/thread), double-buffered.
    f32x4 acc[4][4];
    #pragma unroll
    for (int mt = 0; mt < 4; ++mt)
        #pragma unroll
        for (int nt = 0; nt < 4; ++nt)
            acc[mt][nt] = (f32x4){0.f, 0.f, 0.f, 0.f};
    {
        char* stage = smem + 65536;
        // stage slice ks into buffer sb: 512 thr x 4 x 16B = 32 KB
        #define STAGE_A1(ksl, sb)                                                  \
            {                                                                      \
                const unsigned short* gp = A1 + (ksl) * 16384 + (size_t)t * 8;     \
                char* lp = stage + (sb) * 32768 + w * 1024;                        \
                __builtin_amdgcn_global_load_lds(                                  \
                    (const __attribute__((address_space(1))) unsigned int*)(gp),   \
                    (__attribute__((address_space(3))) unsigned int*)(lp), 16, 0, 0); \
                __builtin_amdgcn_global_load_lds(                                  \
                    (const __attribute__((address_space(1))) unsigned int*)(gp + 4096), \
                    (__attribute__((address_space(3))) unsigned int*)(lp + 8192), 16, 0, 0); \
                __builtin_amdgcn_global_load_lds(                                  \
                    (const __attribute__((address_space(1))) unsigned int*)(gp + 8192), \
                    (__attribute__((address_space(3))) unsigned int*)(lp + 16384), 16, 0, 0); \
                __builtin_amdgcn_global_load_lds(                                  \
                    (const __attribute__((address_space(1))) unsigned int*)(gp + 12288), \
                    (__attribute__((address_space(3))) unsigned int*)(lp + 24576), 16, 0, 0); \
            }

        STAGE_A1(0, 0);
        __syncthreads();   // drains phase-A z1 writes AND slice-0 stage

        const int kofs = (lg << 4) ^ swz5;
        const int rlo = (l15 << 6) + kofs;        // z c = l15
        const int rhi = rlo + 1024;               // z c = 16 + l15
        const int afoff = (w << 12) + (l15 << 6) + (lg << 4);  // row*64 + lg*16

        #pragma unroll
        for (int ks = 0; ks < 16; ++ks) {
            const int cur = ks & 1;
            if (ks < 15) STAGE_A1(ks + 1, cur ^ 1);
            char* ab = stage + cur * 32768;
            bf16x8 af[4], bf[4];
            #pragma unroll
            for (int mt = 0; mt < 4; ++mt)
                af[mt] = *(const bf16x8*)(ab + afoff + mt * 1024);
            bf[0] = *(const bf16x8*)(smem + ks * 2048 + rlo);
            bf[1] = *(const bf16x8*)(smem + ks * 2048 + rhi);
            bf[2] = *(const bf16x8*)(smem + 32768 + ks * 2048 + rlo);
            bf[3] = *(const bf16x8*)(smem + 32768 + ks * 2048 + rhi);
            #pragma unroll
            for (int mt = 0; mt < 4; ++mt)
                #pragma unroll
                for (int nt = 0; nt < 4; ++nt)
                    acc[mt][nt] = __builtin_amdgcn_mfma_f32_16x16x32_bf16(
                        af[mt], bf[nt], acc[mt][nt], 0, 0, 0);
            __syncthreads();   // drain next-slice stage; protect buffers & z1
        }
        #undef STAGE_A1
    }

    // write z2 (bf16): element (k2 = m3*16 + s', n2); s' = lg*4+i -> b64 stores
    {
        #pragma unroll
        for (int mt = 0; mt < 4; ++mt) {
            int n2 = w * 4 + mt;
            int nsw = ((n2 >> 1) & 1) << 5;
            #pragma unroll
            for (int nt = 0; nt < 4; ++nt) {
                char* zb = smem + (nt >> 1) * 32768;
                int m3 = (nt & 1) * 16 + l15;
                uint2 h;
                h.x = cvt2(acc[mt][nt][0], acc[mt][nt][1]);
                h.y = cvt2(acc[mt][nt][2], acc[mt][nt][3]);
                int off = ((m3 >> 1) << 11) + (n2 << 6) +
                          ((((m3 & 1) << 5) + (lg << 3)) ^ nsw);
                *(uint2*)(zb + off) = h;
            }
        }
    }
    __syncthreads();

    // ---- Phase C: wave -> (lb = w>>2, n2h = (w>>1)&1, n3h = w&1) ----
    {
        const int lb = w >> 2, n2h = (w >> 1) & 1, n3h = w & 1;
        const int b  = bq * 2 + lb;
        char* zb = smem + lb * 32768;
        f32x4 c = (f32x4){0.f, 0.f, 0.f, 0.f};
        const unsigned short* w2p = W2T + (n3h * 16 + l15) * 512 + lg * 8;
        const int kofs = (lg << 4) ^ swz5;
        const int n2row = n2h * 16 + l15;
        #pragma unroll 4
        for (int ks = 0; ks < 16; ++ks) {
            bf16x8 bfg = *(const bf16x8*)(w2p + ks * 32);
            bf16x8 af  = *(const bf16x8*)(zb + ks * 2048 + (n2row << 6) + kofs);
            c = __builtin_amdgcn_mfma_f32_16x16x32_bf16(af, bfg, c, 0, 0, 0);
        }
        int n3 = n3h * 16 + l15;
        size_t ob = (size_t)b * 32768 + (size_t)n1 * 1024;
        const float* bp2 = bias + n1 * 1024;
        #pragma unroll
        for (int i = 0; i < 4; ++i) {
            int n2 = n2h * 16 + lg * 4 + i;
            out[ob + n2 * 32 + n3] = c[i] + bp2[n2 * 32 + n3];
        }
    }
}

extern "C" void kernel_launch(void* const* d_in, const int* in_sizes, int n_in,
                              void* d_out, int out_size, void* d_ws, size_t ws_size,
                              hipStream_t stream) {
    (void)in_sizes; (void)n_in; (void)out_size;
    const float* x     = (const float*)d_in[0];
    const float* core0 = (const float*)d_in[1];
    const float* core1 = (const float*)d_in[2];
    const float* core2 = (const float*)d_in[3];
    const float* bias  = (const float*)d_in[4];
    float* out = (float*)d_out;
    unsigned short* ws = (unsigned short*)d_ws;

    const int lds_bytes = 131072;   // 128 KB: 64K z + 64K A1 dbuf
    if (ws_size >= WS_NEED_BYTES) {
        hipFuncSetAttribute((const void*)tt_mfma<true>,
                            hipFuncAttributeMaxDynamicSharedMemorySize, lds_bytes);
        tt_prep<true><<<8336, 256, 0, stream>>>(x, core0, core1, core2, ws);
        tt_mfma<true><<<4096, 512, lds_bytes, stream>>>(x, ws, bias, out);
    } else {
        hipFuncSetAttribute((const void*)tt_mfma<false>,
                            hipFuncAttributeMaxDynamicSharedMemorySize, lds_bytes);
        tt_prep<false><<<144, 256, 0, stream>>>(x, core0, core1, core2, ws);
        tt_mfma<false><<<4096, 512, lds_bytes, stream>>>(x, ws, bias, out);
    }
}

// Round 11
// 256.061 us; speedup vs baseline: 1.4283x; 1.0710x over previous
//
#include <hip/hip_runtime.h>
#include <hip/hip_bf16.h>

// TT layer via bf16 MFMA (gfx950), NB=4, 8 waves, no x-prep (direct f32 reads).
//   Phase A: z1[b][k'=m2*16+r][m3]  = core0[n1]^T . x[b]   (MFMA 16x16x32;
//            B-frag from 8 direct f32 loads + cvt_pk, no xT prep pass)
//   Phase B: z2[b][k2=m3*16+s'][n2] = A1[512,512] . z1     (MFMA 32x32x16,
//            wave tile M=64 x N=128 -> acc[2][4] f32x16 = 128 AGPR)
//   Phase C: y[b][n2,n3] = z2 . W2T^T + bias               (MFMA 16x16x32)
// WG = (b-quad, n1): 2048 WGs x 512 thr, 128KB LDS (4 x 32KB z-tile; z2
// overwrites z1 after barrier). 2 waves/SIMD = 256-reg budget (4-wave configs
// spill: unified VGPR+AGPR file).
// LDS z-tile layout: elem(k 0..511, c 0..31) at byte
//   (k>>5)*2048 + c*64 + (((k&31)<<1) ^ ((c>>1&1)<<5))
// XCD-swizzled blockIdx (n1 inner -> 32 co-resident WGs/XCD share x slice in L2).
// d_ws (bf16): A1[(n2*16+s')][(m2*16+r)], A0T[(n1*16+s)][m1], W2T[n3][(m3*16+s')].

typedef __attribute__((ext_vector_type(8)))  short bf16x8;
typedef __attribute__((ext_vector_type(4)))  float f32x4;
typedef __attribute__((ext_vector_type(16))) float f32x16;

#define WS_A1   0
#define WS_A0T  262144
#define WS_W2T  278528

__device__ __forceinline__ unsigned short f2bf(float f) {
    union { float f; unsigned int u; } v; v.f = f;
    unsigned int u = v.u;
    u += 0x7fffu + ((u >> 16) & 1u);   // RNE (inputs finite)
    return (unsigned short)(u >> 16);
}

__device__ __forceinline__ unsigned int cvt2(float a, float b) {
    union { __hip_bfloat162 h; unsigned int u; } v;
    v.h = __float22bfloat162_rn(float2{a, b});   // v_cvt_pk_bf16_f32
    return v.u;
}

// ---------------- prep: core transforms only (1.2 MB writes, ~trivial) --------
__global__ void tt_prep(const float* __restrict__ core0,
                        const float* __restrict__ core1,
                        const float* __restrict__ core2,
                        unsigned short* __restrict__ ws)
{
    const int u = blockIdx.x * 256 + threadIdx.x;
    unsigned short* A1  = ws + WS_A1;    // [512 rows=(n2*16+s')][512 cols=(m2*16+r)]
    unsigned short* A0T = ws + WS_A0T;   // [512 rows=(n1*16+s)][32 m1]
    unsigned short* W2T = ws + WS_W2T;   // [32 n3][512 k2=(m3*16+s')]
    bf16x8 o;
    if (u < 32768) {
        int e = u * 8;
        int row = e >> 9, col0 = e & 511;
        int n2 = row >> 4, s = row & 15;
        int m2 = col0 >> 4, r0 = col0 & 15;   // r0 in {0,8}
        const float* src = core1 + n2 * 512 + m2 * 16 + s;
        #pragma unroll
        for (int j = 0; j < 8; ++j) o[j] = (short)f2bf(src[(r0 + j) * 16384]);
        *(bf16x8*)(A1 + e) = o;
    } else if (u < 34816) {
        int e = (u - 32768) * 8;
        int row = e >> 5, m1b = e & 31;    // row = n1*16 + s
        int n1 = row >> 4, s = row & 15;
        const float* src = core0 + n1 * 512 + m1b * 16 + s;
        #pragma unroll
        for (int j = 0; j < 8; ++j) o[j] = (short)f2bf(src[j * 16]);
        *(bf16x8*)(A0T + e) = o;
    } else if (u < 36864) {
        int e = (u - 34816) * 8;
        int n3 = e >> 9, k20 = e & 511;
        int m3 = k20 >> 4, s0 = k20 & 15;  // s0 in {0,8}
        const float* src = core2 + n3 * 32 + m3;
        #pragma unroll
        for (int j = 0; j < 8; ++j) o[j] = (short)f2bf(src[(s0 + j) * 1024]);
        *(bf16x8*)(W2T + e) = o;
    }
}

// ---------------- main fused kernel ----------------
__global__ __launch_bounds__(512, 2)
void tt_mfma(const float* __restrict__ x,
             const unsigned short* __restrict__ ws,
             const float* __restrict__ bias,
             float* __restrict__ out)
{
    extern __shared__ char smem[];   // 4 x 32KB: z-tile per local b

    const unsigned short* A1  = ws + WS_A1;
    const unsigned short* A0T = ws + WS_A0T;
    const unsigned short* W2T = ws + WS_W2T;

    const int t   = threadIdx.x;
    const int l   = t & 63;
    const int w   = t >> 6;        // wave 0..7
    const int l15 = l & 15;
    const int lg  = l >> 4;        // 0..3

    // XCD-aware bijective swizzle: 2048 WGs, 8 XCDs, 256 per XCD (n1 inner).
    const int swzid = (blockIdx.x & 7) * 256 + (blockIdx.x >> 3);
    const int bq = swzid >> 5;
    const int n1 = swzid & 31;

    const int swz5 = ((l15 >> 1) & 1) << 5;

    // ---- Phase A: wave -> (lb = w>>1, p-half = w&1); 32 MFMAs ----
    // B-frag: 8 direct f32 loads from x (independent addrs -> ILP-8) + cvt_pk.
    {
        const int lb = w >> 1, ph = w & 1;
        const int b  = bq * 4 + lb;
        char* zb = smem + lb * 32768;
        bf16x8 afrag = *(const bf16x8*)(A0T + n1 * 512 + l15 * 32 + lg * 8);
        const float* xb = x + (size_t)b * 32768 + lg * 8192 + ph * 512 + l15;
        #pragma unroll 2
        for (int pti = 0; pti < 32; ++pti) {
            const float* xp = xb + pti * 16;
            float v0 = xp[0],    v1 = xp[1024], v2 = xp[2048], v3 = xp[3072];
            float v4 = xp[4096], v5 = xp[5120], v6 = xp[6144], v7 = xp[7168];
            uint4 hh;
            hh.x = cvt2(v0, v1); hh.y = cvt2(v2, v3);
            hh.z = cvt2(v4, v5); hh.w = cvt2(v6, v7);
            bf16x8 bfrag = *(bf16x8*)&hh;
            f32x4 c = __builtin_amdgcn_mfma_f32_16x16x32_bf16(
                afrag, bfrag, (f32x4){0.f, 0.f, 0.f, 0.f}, 0, 0, 0);
            int p = ph * 512 + pti * 16 + l15;
            int m2 = p >> 5, m3 = p & 31;
            uint2 h;
            h.x = cvt2(c[0], c[1]);
            h.y = cvt2(c[2], c[3]);
            // k' = m2*16 + (lg*4+i)
            int off = ((m2 >> 1) << 11) + (m3 << 6) +
                      ((((m2 & 1) << 5) + (lg << 3)) ^ (((m3 >> 1) & 1) << 5));
            *(uint2*)(zb + off) = h;
        }
    }
    __syncthreads();

    // ---- Phase B (32x32x16): wave w owns M rows [w*64,+64); N = 128 (4 b) ----
    // A row = l&31 (+32 per mt); B col = l&31 = m3 of tile nt; k = 16*step+8*hi.
    f32x16 acc[2][4];
    #pragma unroll
    for (int mt = 0; mt < 2; ++mt)
        #pragma unroll
        for (int nt = 0; nt < 4; ++nt)
            acc[mt][nt] = (f32x16){0.f,0.f,0.f,0.f,0.f,0.f,0.f,0.f,
                                   0.f,0.f,0.f,0.f,0.f,0.f,0.f,0.f};
    const int c31 = l & 31;
    const int hi  = l >> 5;
    {
        const unsigned short* a1p = A1 + (size_t)(w * 64 + c31) * 512 + hi * 8;
        const int zsw = ((c31 >> 1) & 1) << 5;
        const int zco = c31 << 6;
        #pragma unroll 4
        for (int step = 0; step < 32; ++step) {
            bf16x8 af0 = *(const bf16x8*)(a1p + step * 16);
            bf16x8 af1 = *(const bf16x8*)(a1p + 16384 + step * 16);
            int zoff = ((step >> 1) << 11) + zco +
                       ((((step & 1) << 5) + (hi << 4)) ^ zsw);
            bf16x8 b0 = *(const bf16x8*)(smem + zoff);
            bf16x8 b1 = *(const bf16x8*)(smem + 32768  + zoff);
            bf16x8 b2 = *(const bf16x8*)(smem + 65536  + zoff);
            bf16x8 b3 = *(const bf16x8*)(smem + 98304  + zoff);
            acc[0][0] = __builtin_amdgcn_mfma_f32_32x32x16_bf16(af0, b0, acc[0][0], 0, 0, 0);
            acc[0][1] = __builtin_amdgcn_mfma_f32_32x32x16_bf16(af0, b1, acc[0][1], 0, 0, 0);
            acc[0][2] = __builtin_amdgcn_mfma_f32_32x32x16_bf16(af0, b2, acc[0][2], 0, 0, 0);
            acc[0][3] = __builtin_amdgcn_mfma_f32_32x32x16_bf16(af0, b3, acc[0][3], 0, 0, 0);
            acc[1][0] = __builtin_amdgcn_mfma_f32_32x32x16_bf16(af1, b0, acc[1][0], 0, 0, 0);
            acc[1][1] = __builtin_amdgcn_mfma_f32_32x32x16_bf16(af1, b1, acc[1][1], 0, 0, 0);
            acc[1][2] = __builtin_amdgcn_mfma_f32_32x32x16_bf16(af1, b2, acc[1][2], 0, 0, 0);
            acc[1][3] = __builtin_amdgcn_mfma_f32_32x32x16_bf16(af1, b3, acc[1][3], 0, 0, 0);
        }
    }
    __syncthreads();   // all z1 reads complete

    // write z2: D(32x32) lane l, reg r -> row = 4*hi + (r&3) + 8*(r>>2) (+base),
    // col = m3 = c31. k2 = m3*16 + s'. Pack r&3 (4 consecutive s') as uint2.
    {
        #pragma unroll
        for (int mt = 0; mt < 2; ++mt) {
            #pragma unroll
            for (int nt = 0; nt < 4; ++nt) {
                char* zb = smem + nt * 32768;
                #pragma unroll
                for (int g = 0; g < 4; ++g) {
                    int n2 = w * 4 + mt * 2 + (g >> 1);
                    uint2 h;
                    h.x = cvt2(acc[mt][nt][4 * g],     acc[mt][nt][4 * g + 1]);
                    h.y = cvt2(acc[mt][nt][4 * g + 2], acc[mt][nt][4 * g + 3]);
                    // k2base = m3*16 + 4*hi + 8*(g&1)
                    int inoff = (((c31 & 1) << 5) + (hi << 3) + ((g & 1) << 4)) ^
                                (((n2 >> 1) & 1) << 5);
                    int off = ((c31 >> 1) << 11) + (n2 << 6) + inoff;
                    *(uint2*)(zb + off) = h;
                }
            }
        }
    }
    __syncthreads();

    // ---- Phase C: wave -> (lb = w>>1, n3-half = w&1); y = z2 . W2T^T + bias ----
    {
        const int lb = w >> 1, n3h = w & 1;
        const int b  = bq * 4 + lb;
        char* zb = smem + lb * 32768;
        f32x4 c[2];
        c[0] = (f32x4){0.f, 0.f, 0.f, 0.f};
        c[1] = (f32x4){0.f, 0.f, 0.f, 0.f};
        const unsigned short* w2p = W2T + (n3h * 16 + l15) * 512 + lg * 8;
        const int kofs = (lg << 4) ^ swz5;
        #pragma unroll 4
        for (int ks = 0; ks < 16; ++ks) {
            bf16x8 bfg = *(const bf16x8*)(w2p + ks * 32);
            #pragma unroll
            for (int mt = 0; mt < 2; ++mt) {
                int n2 = mt * 16 + l15;
                bf16x8 af = *(const bf16x8*)(zb + ks * 2048 + (n2 << 6) + kofs);
                c[mt] = __builtin_amdgcn_mfma_f32_16x16x32_bf16(af, bfg, c[mt], 0, 0, 0);
            }
        }
        int n3 = n3h * 16 + l15;
        size_t ob = (size_t)b * 32768 + (size_t)n1 * 1024;
        const float* bp2 = bias + n1 * 1024;
        #pragma unroll
        for (int mt = 0; mt < 2; ++mt)
            #pragma unroll
            for (int i = 0; i < 4; ++i) {
                int n2 = mt * 16 + lg * 4 + i;
                out[ob + n2 * 32 + n3] = c[mt][i] + bp2[n2 * 32 + n3];
            }
    }
}

extern "C" void kernel_launch(void* const* d_in, const int* in_sizes, int n_in,
                              void* d_out, int out_size, void* d_ws, size_t ws_size,
                              hipStream_t stream) {
    (void)in_sizes; (void)n_in; (void)out_size; (void)ws_size;
    const float* x     = (const float*)d_in[0];
    const float* core0 = (const float*)d_in[1];
    const float* core1 = (const float*)d_in[2];
    const float* core2 = (const float*)d_in[3];
    const float* bias  = (const float*)d_in[4];
    float* out = (float*)d_out;
    unsigned short* ws = (unsigned short*)d_ws;   // needs 576 KB

    const int lds_bytes = 4 * 32768;   // 128 KB -> 1 WG/CU
    hipFuncSetAttribute((const void*)tt_mfma,
                        hipFuncAttributeMaxDynamicSharedMemorySize, lds_bytes);
    tt_prep<<<144, 256, 0, stream>>>(core0, core1, core2, ws);
    tt_mfma<<<2048, 512, lds_bytes, stream>>>(x, ws, bias, out);
}

// Round 12
// 229.172 us; speedup vs baseline: 1.5958x; 1.1173x over previous
//
#include <hip/hip_runtime.h>
#include <hip/hip_bf16.h>

// TT layer via bf16 MFMA (gfx950), NB=4, 8 waves, xT-prep, 32x32x16 phase B.
//   Phase A: z1[b][k'=m2*16+r][m3]  = core0[n1]^T . x[b]   (MFMA 16x16x32,
//            B-frags = b128 loads from prepped xT)
//   Phase B: z2[b][k2=m3*16+s'][n2] = A1[512,512] . z1     (MFMA 32x32x16,
//            wave tile M=64 x N=128 -> acc[2][4] f32x16 = 128 AGPR)
//   Phase C: y[b][n2,n3] = z2 . W2T^T + bias               (MFMA 16x16x32)
// WG = (b-quad, n1): 2048 WGs x 512 thr, 128KB LDS (4 x 32KB z-tile; z2
// overwrites z1 after barrier). 2 waves/SIMD = 256-reg budget.
// LDS z-tile layout: elem(k 0..511, c 0..31) at byte
//   (k>>5)*2048 + c*64 + (((k&31)<<1) ^ ((c>>1&1)<<5))
// XCD-swizzled blockIdx (n1 inner). d_ws (bf16): A1[(n2*16+s')][(m2*16+r)],
//   A0T[(n1*16+s)][m1], W2T[n3][(m3*16+s')], xT[b][p][m1].

typedef __attribute__((ext_vector_type(8)))  short bf16x8;
typedef __attribute__((ext_vector_type(4)))  float f32x4;
typedef __attribute__((ext_vector_type(16))) float f32x16;

#define WS_A1   0
#define WS_A0T  262144
#define WS_W2T  278528
#define WS_XT   294912
#define WS_XT_ELEMS 8388608
#define WS_NEED_BYTES ((size_t)(WS_XT + WS_XT_ELEMS) * 2)

__device__ __forceinline__ unsigned short f2bf(float f) {
    union { float f; unsigned int u; } v; v.f = f;
    unsigned int u = v.u;
    u += 0x7fffu + ((u >> 16) & 1u);   // RNE (inputs finite)
    return (unsigned short)(u >> 16);
}

__device__ __forceinline__ unsigned int cvt2(float a, float b) {
    union { __hip_bfloat162 h; unsigned int u; } v;
    v.h = __float22bfloat162_rn(float2{a, b});   // v_cvt_pk_bf16_f32
    return v.u;
}

// ---------------- prep: core transforms (+ optional x transpose) ----------------
template<bool XT>
__global__ void tt_prep(const float* __restrict__ x,
                        const float* __restrict__ core0,
                        const float* __restrict__ core1,
                        const float* __restrict__ core2,
                        unsigned short* __restrict__ ws)
{
    const int t = threadIdx.x;
    if (XT && blockIdx.x < 8192) {
        // transpose x[b][m1][m2*32+m3] (f32) -> xT[b][p=m2*32+m3][m1] (bf16)
        __shared__ float tile[32 * 36];
        const int b  = blockIdx.x >> 5;
        const int m2 = blockIdx.x & 31;
        {
            const int m1 = t >> 3, c4 = (t & 7) * 4;
            float4 v = *(const float4*)(x + (size_t)b * 32768 + m1 * 1024 + m2 * 32 + c4);
            *(float4*)&tile[m1 * 36 + c4] = v;
        }
        __syncthreads();
        {
            const int m3 = t >> 3, g = t & 7;
            unsigned short o[4];
            #pragma unroll
            for (int j = 0; j < 4; ++j)
                o[j] = f2bf(tile[(g * 4 + j) * 36 + m3]);
            unsigned short* dst = ws + WS_XT + (size_t)b * 32768 + (m2 * 32 + m3) * 32 + g * 4;
            *(uint2*)dst = *(uint2*)o;
        }
        return;
    }
    const int u = (blockIdx.x - (XT ? 8192 : 0)) * 256 + t;
    unsigned short* A1  = ws + WS_A1;    // [512 rows=(n2*16+s')][512 cols=(m2*16+r)]
    unsigned short* A0T = ws + WS_A0T;   // [512 rows=(n1*16+s)][32 m1]
    unsigned short* W2T = ws + WS_W2T;   // [32 n3][512 k2=(m3*16+s')]
    bf16x8 o;
    if (u < 32768) {
        int e = u * 8;
        int row = e >> 9, col0 = e & 511;
        int n2 = row >> 4, s = row & 15;
        int m2 = col0 >> 4, r0 = col0 & 15;   // r0 in {0,8}
        const float* src = core1 + n2 * 512 + m2 * 16 + s;
        #pragma unroll
        for (int j = 0; j < 8; ++j) o[j] = (short)f2bf(src[(r0 + j) * 16384]);
        *(bf16x8*)(A1 + e) = o;
    } else if (u < 34816) {
        int e = (u - 32768) * 8;
        int row = e >> 5, m1b = e & 31;    // row = n1*16 + s
        int n1 = row >> 4, s = row & 15;
        const float* src = core0 + n1 * 512 + m1b * 16 + s;
        #pragma unroll
        for (int j = 0; j < 8; ++j) o[j] = (short)f2bf(src[j * 16]);
        *(bf16x8*)(A0T + e) = o;
    } else if (u < 36864) {
        int e = (u - 34816) * 8;
        int n3 = e >> 9, k20 = e & 511;
        int m3 = k20 >> 4, s0 = k20 & 15;  // s0 in {0,8}
        const float* src = core2 + n3 * 32 + m3;
        #pragma unroll
        for (int j = 0; j < 8; ++j) o[j] = (short)f2bf(src[(s0 + j) * 1024]);
        *(bf16x8*)(W2T + e) = o;
    }
}

// ---------------- main fused kernel ----------------
template<bool XT>
__global__ __launch_bounds__(512, 2)
void tt_mfma(const float* __restrict__ x,
             const unsigned short* __restrict__ ws,
             const float* __restrict__ bias,
             float* __restrict__ out)
{
    extern __shared__ char smem[];   // 4 x 32KB: z-tile per local b

    const unsigned short* A1  = ws + WS_A1;
    const unsigned short* A0T = ws + WS_A0T;
    const unsigned short* W2T = ws + WS_W2T;
    const unsigned short* xT  = ws + WS_XT;

    const int t   = threadIdx.x;
    const int l   = t & 63;
    const int w   = t >> 6;        // wave 0..7
    const int l15 = l & 15;
    const int lg  = l >> 4;        // 0..3

    // XCD-aware bijective swizzle: 2048 WGs, 8 XCDs, 256 per XCD (n1 inner).
    const int swzid = (blockIdx.x & 7) * 256 + (blockIdx.x >> 3);
    const int bq = swzid >> 5;
    const int n1 = swzid & 31;

    const int swz5 = ((l15 >> 1) & 1) << 5;

    // ---- Phase A: wave -> (lb = w>>1, p-half = w&1); 32 MFMAs, dbuf'd ----
    {
        const int lb = w >> 1, ph = w & 1;
        const int b  = bq * 4 + lb;
        char* zb = smem + lb * 32768;
        bf16x8 afrag = *(const bf16x8*)(A0T + n1 * 512 + l15 * 32 + lg * 8);
        if (XT) {
            const unsigned short* xb = xT + (size_t)b * 32768 + lg * 8;
            bf16x8 bfrag[2];
            bfrag[0] = *(const bf16x8*)(xb + (ph * 512 + l15) * 32);
            #pragma unroll
            for (int pti = 0; pti < 32; ++pti) {
                if (pti < 31) {
                    int pn = ph * 512 + (pti + 1) * 16 + l15;
                    bfrag[(pti + 1) & 1] = *(const bf16x8*)(xb + pn * 32);
                }
                int p = ph * 512 + pti * 16 + l15;
                f32x4 c = __builtin_amdgcn_mfma_f32_16x16x32_bf16(
                    afrag, bfrag[pti & 1], (f32x4){0.f, 0.f, 0.f, 0.f}, 0, 0, 0);
                int m2 = p >> 5, m3 = p & 31;
                uint2 h;
                h.x = cvt2(c[0], c[1]);
                h.y = cvt2(c[2], c[3]);
                // k' = m2*16 + (lg*4+i)
                int off = ((m2 >> 1) << 11) + (m3 << 6) +
                          ((((m2 & 1) << 5) + (lg << 3)) ^ (((m3 >> 1) & 1) << 5));
                *(uint2*)(zb + off) = h;
            }
        } else {
            const float* xb = x + (size_t)b * 32768 + (lg * 8) * 1024;
            for (int pti = 0; pti < 32; ++pti) {
                int p = ph * 512 + pti * 16 + l15;
                bf16x8 bfrag;
                #pragma unroll
                for (int j = 0; j < 8; ++j) bfrag[j] = (short)f2bf(xb[j * 1024 + p]);
                f32x4 c = __builtin_amdgcn_mfma_f32_16x16x32_bf16(
                    afrag, bfrag, (f32x4){0.f, 0.f, 0.f, 0.f}, 0, 0, 0);
                int m2 = p >> 5, m3 = p & 31;
                uint2 h;
                h.x = cvt2(c[0], c[1]);
                h.y = cvt2(c[2], c[3]);
                int off = ((m2 >> 1) << 11) + (m3 << 6) +
                          ((((m2 & 1) << 5) + (lg << 3)) ^ (((m3 >> 1) & 1) << 5));
                *(uint2*)(zb + off) = h;
            }
        }
    }
    __syncthreads();

    // ---- Phase B (32x32x16): wave w owns M rows [w*64,+64); N = 128 (4 b) ----
    // A row = l&31 (+32 for mt=1); B col = l&31 = m3; k = 16*step + 8*hi.
    f32x16 acc[2][4];
    #pragma unroll
    for (int mt = 0; mt < 2; ++mt)
        #pragma unroll
        for (int nt = 0; nt < 4; ++nt)
            acc[mt][nt] = (f32x16){0.f,0.f,0.f,0.f,0.f,0.f,0.f,0.f,
                                   0.f,0.f,0.f,0.f,0.f,0.f,0.f,0.f};
    const int c31 = l & 31;
    const int hi  = l >> 5;
    {
        const unsigned short* a1p = A1 + (size_t)(w * 64 + c31) * 512 + hi * 8;
        const int zsw = ((c31 >> 1) & 1) << 5;
        const int zco = c31 << 6;
        #pragma unroll 4
        for (int step = 0; step < 32; ++step) {
            bf16x8 af0 = *(const bf16x8*)(a1p + step * 16);
            bf16x8 af1 = *(const bf16x8*)(a1p + 16384 + step * 16);
            int zoff = ((step >> 1) << 11) + zco +
                       ((((step & 1) << 5) + (hi << 4)) ^ zsw);
            bf16x8 b0 = *(const bf16x8*)(smem + zoff);
            bf16x8 b1 = *(const bf16x8*)(smem + 32768  + zoff);
            bf16x8 b2 = *(const bf16x8*)(smem + 65536  + zoff);
            bf16x8 b3 = *(const bf16x8*)(smem + 98304  + zoff);
            acc[0][0] = __builtin_amdgcn_mfma_f32_32x32x16_bf16(af0, b0, acc[0][0], 0, 0, 0);
            acc[0][1] = __builtin_amdgcn_mfma_f32_32x32x16_bf16(af0, b1, acc[0][1], 0, 0, 0);
            acc[0][2] = __builtin_amdgcn_mfma_f32_32x32x16_bf16(af0, b2, acc[0][2], 0, 0, 0);
            acc[0][3] = __builtin_amdgcn_mfma_f32_32x32x16_bf16(af0, b3, acc[0][3], 0, 0, 0);
            acc[1][0] = __builtin_amdgcn_mfma_f32_32x32x16_bf16(af1, b0, acc[1][0], 0, 0, 0);
            acc[1][1] = __builtin_amdgcn_mfma_f32_32x32x16_bf16(af1, b1, acc[1][1], 0, 0, 0);
            acc[1][2] = __builtin_amdgcn_mfma_f32_32x32x16_bf16(af1, b2, acc[1][2], 0, 0, 0);
            acc[1][3] = __builtin_amdgcn_mfma_f32_32x32x16_bf16(af1, b3, acc[1][3], 0, 0, 0);
        }
    }
    __syncthreads();   // all z1 reads complete

    // write z2: D(32x32) lane l, reg r -> row = 4*hi + (r&3) + 8*(r>>2) (+base),
    // col = m3 = c31. k2 = m3*16 + s'. Pack (r&3) as uint2 pairs.
    {
        #pragma unroll
        for (int mt = 0; mt < 2; ++mt) {
            #pragma unroll
            for (int nt = 0; nt < 4; ++nt) {
                char* zb = smem + nt * 32768;
                #pragma unroll
                for (int g = 0; g < 4; ++g) {
                    int n2 = w * 4 + mt * 2 + (g >> 1);
                    uint2 h;
                    h.x = cvt2(acc[mt][nt][4 * g],     acc[mt][nt][4 * g + 1]);
                    h.y = cvt2(acc[mt][nt][4 * g + 2], acc[mt][nt][4 * g + 3]);
                    // k2base = m3*16 + 4*hi + 8*(g&1)
                    int inoff = (((c31 & 1) << 5) + (hi << 3) + ((g & 1) << 4)) ^
                                (((n2 >> 1) & 1) << 5);
                    int off = ((c31 >> 1) << 11) + (n2 << 6) + inoff;
                    *(uint2*)(zb + off) = h;
                }
            }
        }
    }
    __syncthreads();

    // ---- Phase C: wave -> (lb = w>>1, n3-half = w&1); y = z2 . W2T^T + bias ----
    {
        const int lb = w >> 1, n3h = w & 1;
        const int b  = bq * 4 + lb;
        char* zb = smem + lb * 32768;
        f32x4 c[2];
        c[0] = (f32x4){0.f, 0.f, 0.f, 0.f};
        c[1] = (f32x4){0.f, 0.f, 0.f, 0.f};
        const unsigned short* w2p = W2T + (n3h * 16 + l15) * 512 + lg * 8;
        const int kofs = (lg << 4) ^ swz5;
        bf16x8 bfg[2];
        bfg[0] = *(const bf16x8*)(w2p);
        #pragma unroll
        for (int ks = 0; ks < 16; ++ks) {
            if (ks < 15) bfg[(ks + 1) & 1] = *(const bf16x8*)(w2p + (ks + 1) * 32);
            #pragma unroll
            for (int mt = 0; mt < 2; ++mt) {
                int n2 = mt * 16 + l15;
                bf16x8 af = *(const bf16x8*)(zb + ks * 2048 + (n2 << 6) + kofs);
                c[mt] = __builtin_amdgcn_mfma_f32_16x16x32_bf16(af, bfg[ks & 1], c[mt], 0, 0, 0);
            }
        }
        int n3 = n3h * 16 + l15;
        size_t ob = (size_t)b * 32768 + (size_t)n1 * 1024;
        const float* bp2 = bias + n1 * 1024;
        #pragma unroll
        for (int mt = 0; mt < 2; ++mt)
            #pragma unroll
            for (int i = 0; i < 4; ++i) {
                int n2 = mt * 16 + lg * 4 + i;
                out[ob + n2 * 32 + n3] = c[mt][i] + bp2[n2 * 32 + n3];
            }
    }
}

extern "C" void kernel_launch(void* const* d_in, const int* in_sizes, int n_in,
                              void* d_out, int out_size, void* d_ws, size_t ws_size,
                              hipStream_t stream) {
    (void)in_sizes; (void)n_in; (void)out_size;
    const float* x     = (const float*)d_in[0];
    const float* core0 = (const float*)d_in[1];
    const float* core1 = (const float*)d_in[2];
    const float* core2 = (const float*)d_in[3];
    const float* bias  = (const float*)d_in[4];
    float* out = (float*)d_out;
    unsigned short* ws = (unsigned short*)d_ws;

    const int lds_bytes = 4 * 32768;   // 128 KB -> 1 WG/CU
    if (ws_size >= WS_NEED_BYTES) {
        hipFuncSetAttribute((const void*)tt_mfma<true>,
                            hipFuncAttributeMaxDynamicSharedMemorySize, lds_bytes);
        tt_prep<true><<<8336, 256, 0, stream>>>(x, core0, core1, core2, ws);
        tt_mfma<true><<<2048, 512, lds_bytes, stream>>>(x, ws, bias, out);
    } else {
        hipFuncSetAttribute((const void*)tt_mfma<false>,
                            hipFuncAttributeMaxDynamicSharedMemorySize, lds_bytes);
        tt_prep<false><<<144, 256, 0, stream>>>(x, core0, core1, core2, ws);
        tt_mfma<false><<<2048, 512, lds_bytes, stream>>>(x, ws, bias, out);
    }
}